// Round 3
// baseline (242.169 us; speedup 1.0000x reference)
//
#include <hip/hip_runtime.h>

// CubicHermite2d: B=32, N=1024, axes arange(N) => uniform knots, dx=1.
//
// out[b,k,p] = Hermite_x(h0y*row0 + h2y*row1)(xs[p])
//            + h1y*(row1[p]-row0[p]) + h3y*(row2[p]-row1[p])
//   rows = signal[b, Iy(k)+r, :],  Iy = floor(ys[k]).
//
// R2 structure: 4 k-rows per block (grid 256x32, 256 thr).
//  - x-weights (Ix,w0..w2 per p) computed ONCE per block (were recomputed
//    per-k => 4x redundant VALU across the old 32768-block grid)
//  - 12 independent row float4 loads in flight per thread (4x MLP)
//  - ONE __syncthreads per block (4 combined-row LDS buffers, then gather)
//  - column terms stay in the loading thread's registers (row2 never in LDS)

#define NGRID 1024
#define BATCH 32
#define KPB   4     // k-rows per block

__global__ __launch_bounds__(256) void hermite2d_fused(
    const float* __restrict__ signal,   // [B, N, N]
    const float* __restrict__ xs,       // [N]
    const float* __restrict__ ys,       // [N]
    float* __restrict__ out)            // [B, N(k), N(p)]
{
    const int kg = blockIdx.x;          // k-group: rows kg*4 .. kg*4+3
    const int b  = blockIdx.y;
    const int t  = threadIdx.x;         // owns columns 4t..4t+3
    const int k0 = kg * KPB;

    __shared__ float crow[KPB][NGRID];  // h0y*row0 + h2y*row1, per k

    // ---- x-direction weights: once per block ----
    const float4 q4 = ((const float4*)xs)[t];
    const float qxa[4] = { q4.x, q4.y, q4.z, q4.w };
    int   Ix[4];
    float w0[4], w1[4], w2[4];
    #pragma unroll
    for (int j = 0; j < 4; ++j) {
        const float q = qxa[j];
        int I = (int)floorf(q);
        if (I < 0) I = 0;
        if (I > NGRID - 3) I = NGRID - 3;
        const float tx = q - (float)I;
        const float t2 = tx * tx;
        const float t3 = t2 * tx;
        Ix[j] = I;
        w0[j] = 1.0f - tx - t2 + t3;
        w1[j] = tx + 2.0f * (t2 - t3);
        w2[j] = t3 - t2;
    }

    // ---- y queries for the 4 rows of this block ----
    const float4 y4 = ((const float4*)ys)[kg];
    const float qya[4] = { y4.x, y4.y, y4.z, y4.w };

    float colp[KPB][4];                 // register-resident column terms

    #pragma unroll
    for (int i = 0; i < KPB; ++i) {
        const float qy = qya[i];
        int Iy = (int)floorf(qy);
        if (Iy < 0) Iy = 0;
        if (Iy > NGRID - 3) Iy = NGRID - 3;
        const float ty  = qy - (float)Iy;
        const float ty2 = ty * ty;
        const float ty3 = ty2 * ty;
        const float h0y = 1.0f - 3.0f * ty2 + 2.0f * ty3;
        const float h1y = ty - 2.0f * ty2 + ty3;
        const float h2y = 3.0f * ty2 - 2.0f * ty3;
        const float h3y = ty3 - ty2;

        const float4* src4 =
            (const float4*)(signal + ((size_t)b * NGRID + (size_t)Iy) * NGRID);
        const float4 r0 = src4[t];
        const float4 r1 = src4[t + NGRID / 4];
        const float4 r2 = src4[t + NGRID / 2];

        float4 c;
        c.x = h0y * r0.x + h2y * r1.x;
        c.y = h0y * r0.y + h2y * r1.y;
        c.z = h0y * r0.z + h2y * r1.z;
        c.w = h0y * r0.w + h2y * r1.w;
        ((float4*)crow[i])[t] = c;

        colp[i][0] = h1y * (r1.x - r0.x) + h3y * (r2.x - r1.x);
        colp[i][1] = h1y * (r1.y - r0.y) + h3y * (r2.y - r1.y);
        colp[i][2] = h1y * (r1.z - r0.z) + h3y * (r2.z - r1.z);
        colp[i][3] = h1y * (r1.w - r0.w) + h3y * (r2.w - r1.w);
    }

    __syncthreads();

    // ---- gather + combine + coalesced store, 4 rows ----
    float* orow = out + ((size_t)b * NGRID + (size_t)k0) * NGRID;
    #pragma unroll
    for (int i = 0; i < KPB; ++i) {
        float4 res;
        float* resp = (float*)&res;
        #pragma unroll
        for (int j = 0; j < 4; ++j) {
            const int I = Ix[j];
            const float c0 = crow[i][I];
            const float c1 = crow[i][I + 1];
            const float c2 = crow[i][I + 2];
            resp[j] = w0[j] * c0 + w1[j] * c1 + w2[j] * c2 + colp[i][j];
        }
        ((float4*)(orow + (size_t)i * NGRID))[t] = res;
    }
}

extern "C" void kernel_launch(void* const* d_in, const int* in_sizes, int n_in,
                              void* d_out, int out_size, void* d_ws, size_t ws_size,
                              hipStream_t stream) {
    // inputs: 0=xaxis[N], 1=yaxis[N], 2=signal[B,N,N], 3=xs[N], 4=ys[N] (all f32)
    const float* signal = (const float*)d_in[2];
    const float* xs     = (const float*)d_in[3];
    const float* ys     = (const float*)d_in[4];
    float* out          = (float*)d_out;

    dim3 grid(NGRID / KPB, BATCH);
    hermite2d_fused<<<grid, 256, 0, stream>>>(signal, xs, ys, out);
}